// Round 25
// baseline (293.711 us; speedup 1.0000x reference)
//
#include <hip/hip_runtime.h>
#include <hip/hip_bf16.h>

// BoostedCausalAttention: bf16 MFMA pipeline
// B=2 T=2048 D=1024 H=16 DH=64, fp32 in/out, bf16 internal compute.
// R6 589 -> R8 475 -> R9 352.9 -> R15 309.3 -> R17 302.2 -> R19 297.4 ->
// R21 287.0 -> R24 (verified) 283.1 (T1 GEMM swizzle + xb-resid).
// Attn at 72.4us: MfmaUtil 9%, VALU 40%, Occ 17% — grid 512 = 2 blocks/CU
// is the cap (LDS would allow 3, VGPR 4). Issue/latency-bound.
// R25: SPLIT-K attention — each (qtp,b) pair's KV range [0,qhi] splits at
//   s0=(qhi+2)/2 into two blocks (grid 16x16x4=1024). Partials: normalized
//   o-hat bf16 + per-row m,l fp32; merge kernel combines (guarded 1/l).
//   LDS 48->40KB (ps aliased hi/lo; Q_lo staged in idle ks[1]) -> 4
//   blocks/CU, 1024 blocks fully resident. Merge<1> fuses resid from xb.

typedef __bf16 bf16x8 __attribute__((ext_vector_type(8)));
typedef float f32x4 __attribute__((ext_vector_type(4)));

__device__ __forceinline__ unsigned short f2bf(float f) {
  union { __hip_bfloat16 h; unsigned short u; } cv;
  cv.h = __float2bfloat16(f);
  return cv.u;
}
__device__ __forceinline__ float bf2f(unsigned short u) {
  union { unsigned int u; float f; } cv;
  cv.u = (unsigned int)u << 16;
  return cv.f;
}

#define GLD16(gp, lp) __builtin_amdgcn_global_load_lds(                      \
    (const __attribute__((address_space(1))) void*)(gp),                     \
    (__attribute__((address_space(3))) void*)(lp), 16, 0, 0)

// ---- batched prep: 4x transpose_cast + x cast in one dispatch --------------
__global__ __launch_bounds__(256) void prep_batch(
    const float* __restrict__ W0, __hip_bfloat16* __restrict__ Wt0,
    const float* __restrict__ W1, __hip_bfloat16* __restrict__ Wt1,
    const float* __restrict__ Wg, __hip_bfloat16* __restrict__ Wgt,
    const float* __restrict__ Wo, __hip_bfloat16* __restrict__ Wot,
    const float* __restrict__ x, __hip_bfloat16* __restrict__ xb) {
  const int bid = blockIdx.x;
  if (bid >= 9216) {  // x cast
    size_t e = (((size_t)(bid - 9216)) * 256 + threadIdx.x) * 4;
    float4 v = *(const float4*)(x + e);
    ushort4 o;
    o.x = f2bf(v.x); o.y = f2bf(v.y); o.z = f2bf(v.z); o.w = f2bf(v.w);
    *(ushort4*)((unsigned short*)xb + e) = o;
    return;
  }
  const float* in; __hip_bfloat16* out; int R, C, base;
  if (bid < 3072)      { in = W0; out = Wt0; R = 1024; C = 3072; base = 0; }
  else if (bid < 6144) { in = W1; out = Wt1; R = 1024; C = 3072; base = 3072; }
  else if (bid < 8192) { in = Wg; out = Wgt; R = 2048; C = 1024; base = 6144; }
  else                 { in = Wo; out = Wot; R = 1024; C = 1024; base = 8192; }
  const int local = bid - base, nbx = C / 32;
  const int bx = (local % nbx) * 32, by = (local / nbx) * 32;
  const int tx = threadIdx.x & 31, ty = threadIdx.x >> 5;
  __shared__ float t[32][33];
#pragma unroll
  for (int i = 0; i < 32; i += 8)
    t[ty + i][tx] = in[(size_t)(by + ty + i) * C + bx + tx];
  __syncthreads();
#pragma unroll
  for (int i = 0; i < 32; i += 8)
    out[(size_t)(bx + ty + i) * R + by + tx] = __float2bfloat16(t[tx][ty + i]);
}

// ------- bf16 MFMA GEMM, 128x128 tile, BK=32, dbuf, T1 XCD swizzle ----------
template <int EPI>
__global__ __launch_bounds__(256) void gemm_bf16(
    const __hip_bfloat16* __restrict__ A, const __hip_bfloat16* __restrict__ Bt,
    const float* __restrict__ bias, void* __restrict__ outp,
    const __hip_bfloat16* __restrict__ aux0, const __hip_bfloat16* __restrict__ aux1,
    int M, int N, int K) {
  __shared__ __hip_bfloat16 As[2][128 * 32];
  __shared__ __hip_bfloat16 Bs[2][128 * 32];
  const int tid = threadIdx.x;
  const int lane = tid & 63, wid = tid >> 6;
  const int wr = wid >> 1, wc = wid & 1;
  const int lr = lane & 15, lk = (lane >> 4) * 8;
  const int nbx = N >> 7;
  const int cpx = gridDim.x >> 3;
  const int swz = (blockIdx.x & 7) * cpx + (blockIdx.x >> 3);
  const size_t bcol = (size_t)(swz % nbx) * 128;
  const size_t brow = (size_t)(swz / nbx) * 128;
  f32x4 acc[4][4] = {};
#pragma unroll
  for (int r = 0; r < 2; ++r) {
    int c = tid + r * 256;
    GLD16(A + (brow + (size_t)(c >> 2)) * K + (c & 3) * 8, As[0] + c * 8);
    GLD16(Bt + (bcol + (size_t)(c >> 2)) * K + (c & 3) * 8, Bs[0] + c * 8);
  }
  __syncthreads();
  int cur = 0;
  for (int k0 = 0; k0 < K; k0 += 32) {
    const int nxt = cur ^ 1;
    if (k0 + 32 < K) {
#pragma unroll
      for (int r = 0; r < 2; ++r) {
        int c = tid + r * 256;
        GLD16(A + (brow + (size_t)(c >> 2)) * K + k0 + 32 + (c & 3) * 8,
              As[nxt] + c * 8);
        GLD16(Bt + (bcol + (size_t)(c >> 2)) * K + k0 + 32 + (c & 3) * 8,
              Bs[nxt] + c * 8);
      }
    }
    bf16x8 a[4], b[4];
#pragma unroll
    for (int m = 0; m < 4; ++m)
      a[m] = *(const bf16x8*)(As[cur] + (wr * 64 + m * 16 + lr) * 32 + lk);
#pragma unroll
    for (int n = 0; n < 4; ++n)
      b[n] = *(const bf16x8*)(Bs[cur] + (wc * 64 + n * 16 + lr) * 32 + lk);
#pragma unroll
    for (int m = 0; m < 4; ++m)
#pragma unroll
      for (int n = 0; n < 4; ++n)
        acc[m][n] = __builtin_amdgcn_mfma_f32_16x16x32_bf16(a[m], b[n], acc[m][n], 0, 0, 0);
    __syncthreads();
    cur = nxt;
  }
  const int r0 = (lane >> 4) * 4, cn = lane & 15;
#pragma unroll
  for (int m = 0; m < 4; ++m)
#pragma unroll
    for (int n = 0; n < 4; ++n) {
      size_t col = bcol + wc * 64 + n * 16 + cn;
      float bv = bias[col];
#pragma unroll
      for (int j = 0; j < 4; ++j) {
        size_t row = brow + wr * 64 + m * 16 + r0 + j;
        float v = acc[m][n][j] + bv;
        if constexpr (EPI == 1) {
          float g = 1.0f / (1.0f + __expf(-v));
          float a0 = __bfloat162float(aux0[row * 2048 + col]);
          float a1 = __bfloat162float(aux1[row * 2048 + col]);
          ((__hip_bfloat16*)outp)[row * N + col] = __float2bfloat16(g * a0 + a1);
        } else if constexpr (EPI == 2) {
          ((float*)outp)[row * N + col] = v;
        } else {
          ((__hip_bfloat16*)outp)[row * N + col] = __float2bfloat16(v);
        }
      }
    }
}

// ------- causal flash attention V6 (split-K halves, 40KB LDS) ---------------
// Grid (16,16,4): z -> b=z&1, hf=z>>1. Block covers KV tiles [k0t,k1t) of
// the pair (qlo=qtp, qhi=31-qtp): s0=(qhi+2)>>1; half0 [0,s0), half1 [s0,S).
// Writes normalized partials po[hf] (bf16) + pm/pl[hf] (f32). ps aliased
// (hi/lo sequential, within-call use); Q_lo staged via idle ks[1].
__global__ __launch_bounds__(256) void attn_kernel(
    const __hip_bfloat16* __restrict__ qkv,
    __hip_bfloat16* __restrict__ po, float* __restrict__ pm,
    float* __restrict__ pl) {
  const int zz = blockIdx.z;
  const int b = zz & 1, hf = zz >> 1;
  const int h = blockIdx.y, qtp = blockIdx.x;
  const int qlo = qtp, qhi = 31 - qtp;
  const int S = qhi + 1, s0 = (S + 1) >> 1;
  const int k0t = hf ? s0 : 0;
  const int k1t = hf ? S : s0;
  __shared__ __hip_bfloat16 ks[2][64 * 64];
  __shared__ __hip_bfloat16 vts[2][64 * 64];  // V^T [dh][kv], swizzled
  __shared__ __hip_bfloat16 qps[4096];        // Q_hi staging -> shared ps
  const int tid = threadIdx.x, lane = tid & 63, w = tid >> 6;
  const int lr = lane & 15, lg = lane >> 4;
  const int sw = lr & 7;
  const size_t rs = 3072;
  const int q0lo = qlo * 64, q0hi = qhi * 64;
  const __hip_bfloat16* qbh = qkv + ((size_t)b * 2048 + q0hi) * rs + h * 64;
  const __hip_bfloat16* qbl = qkv + ((size_t)b * 2048 + q0lo) * rs + h * 64;
  const __hip_bfloat16* kb = qkv + (size_t)b * 2048 * rs + 1024 + h * 64;
  const __hip_bfloat16* vb = qkv + (size_t)b * 2048 * rs + 2048 + h * 64;

  const int vrow2 = tid >> 3, vseg = tid & 7;
  float4 vr0, vr1;
  {  // prologue: Q_hi->qps, Q_lo->ks[1] (idle), K(k0t)->ks[0], V(k0t)->regs
    const int kvr = k0t * 64;
#pragma unroll
    for (int r = 0; r < 2; ++r) {
      int c = tid + r * 256, row = c >> 3, p = c & 7;
      GLD16(qbh + (size_t)row * rs + (p ^ (row & 7)) * 8, qps + c * 8);
      GLD16(qbl + (size_t)row * rs + (p ^ (row & 7)) * 8, ks[1] + c * 8);
      GLD16(kb + (size_t)(kvr + row) * rs + (p ^ (row & 7)) * 8, ks[0] + c * 8);
    }
    vr0 = *(const float4*)(vb + (size_t)(kvr + 2 * vrow2) * rs + vseg * 8);
    vr1 = *(const float4*)(vb + (size_t)(kvr + 2 * vrow2 + 1) * rs + vseg * 8);
  }
  __syncthreads();
  const int qrow = w * 16 + lr;
  const bf16x8 qh0 = *(const bf16x8*)(qps + qrow * 64 + ((lg) ^ (qrow & 7)) * 8);
  const bf16x8 qh1 = *(const bf16x8*)(qps + qrow * 64 + ((4 + lg) ^ (qrow & 7)) * 8);
  const bf16x8 ql0 = *(const bf16x8*)(ks[1] + qrow * 64 + ((lg) ^ (qrow & 7)) * 8);
  const bf16x8 ql1 = *(const bf16x8*)(ks[1] + qrow * 64 + ((4 + lg) ^ (qrow & 7)) * 8);
  {
    const unsigned short* u0 = (const unsigned short*)&vr0;
    const unsigned short* u1 = (const unsigned short*)&vr1;
#pragma unroll
    for (int i = 0; i < 8; ++i) {
      const int dh = vseg * 8 + i;
      const int phys = (vrow2 >> 2) ^ (dh & 7) ^ ((dh >> 3) & 7);
      unsigned int pk = (unsigned int)u0[i] | ((unsigned int)u1[i] << 16);
      *(unsigned int*)(vts[0] + dh * 64 + phys * 8 + 2 * (vrow2 & 3)) = pk;
    }
  }
  __syncthreads();  // Q frags in regs; qps free for ps, ks[1] free for prefetch

  __hip_bfloat16* psw = qps + w * 1024;  // wave-private, aliased hi/lo
  float m_hi = -1e30f, l_hi = 0.f, m_lo = -1e30f, l_lo = 0.f;
  f32x4 o_hi[4] = {}, o_lo[4] = {};
  int cur = 0;

  auto process = [&](const bf16x8& qa0, const bf16x8& qa1, bool diag,
                     float& m_run, float& l_run, f32x4* o) {
    f32x4 s4[4] = {};
    __builtin_amdgcn_s_setprio(1);
#pragma unroll
    for (int n = 0; n < 4; ++n) {
      const int kr = n * 16 + lr;
      bf16x8 k0f = *(const bf16x8*)(ks[cur] + kr * 64 + ((lg) ^ sw) * 8);
      bf16x8 k1f = *(const bf16x8*)(ks[cur] + kr * 64 + ((4 + lg) ^ sw) * 8);
      s4[n] = __builtin_amdgcn_mfma_f32_16x16x32_bf16(k0f, qa0, s4[n], 0, 0, 0);
      s4[n] = __builtin_amdgcn_mfma_f32_16x16x32_bf16(k1f, qa1, s4[n], 0, 0, 0);
    }
    __builtin_amdgcn_s_setprio(0);
    float p[4][4];
    float mloc = -1e30f;
#pragma unroll
    for (int n = 0; n < 4; ++n)
#pragma unroll
      for (int j = 0; j < 4; ++j) {
        float v = s4[n][j] * 0.125f;
        if (diag && (n * 16 + lg * 4 + j) > (w * 16 + lr)) v = -1e30f;
        p[n][j] = v;
        mloc = fmaxf(mloc, v);
      }
    mloc = fmaxf(mloc, __shfl_xor(mloc, 16));
    mloc = fmaxf(mloc, __shfl_xor(mloc, 32));
    if (!__all(mloc - m_run <= 8.0f)) {  // T13 defer-max
      const float mn = fmaxf(m_run, mloc);
      const float sc = __expf(m_run - mn);
      m_run = mn;
      l_run *= sc;
      float scb[4];
#pragma unroll
      for (int j = 0; j < 4; ++j) scb[j] = __shfl(sc, lg * 4 + j);
#pragma unroll
      for (int n = 0; n < 4; ++n)
#pragma unroll
        for (int j = 0; j < 4; ++j) o[n][j] *= scb[j];
    }
    float ls = 0.f;
#pragma unroll
    for (int n = 0; n < 4; ++n)
#pragma unroll
      for (int j = 0; j < 4; ++j) { p[n][j] = __expf(p[n][j] - m_run); ls += p[n][j]; }
    ls += __shfl_xor(ls, 16);
    ls += __shfl_xor(ls, 32);
    l_run += ls;
#pragma unroll
    for (int n = 0; n < 4; ++n)
#pragma unroll
      for (int j = 0; j < 4; ++j)
        psw[lr * 64 + ((n * 2 + (lg >> 1)) ^ sw) * 8 + (lg & 1) * 4 + j] =
            __float2bfloat16(p[n][j]);
    bf16x8 pa0 = *(const bf16x8*)(&psw[lr * 64 + ((lg) ^ sw) * 8]);
    bf16x8 pa1 = *(const bf16x8*)(&psw[lr * 64 + ((4 + lg) ^ sw) * 8]);
    __builtin_amdgcn_s_setprio(1);
#pragma unroll
    for (int n = 0; n < 4; ++n) {
      const int vdh = n * 16 + lr;
      const int swv = (vdh & 7) ^ ((vdh >> 3) & 7);
      bf16x8 v0f = *(const bf16x8*)(vts[cur] + vdh * 64 + ((lg) ^ swv) * 8);
      bf16x8 v1f = *(const bf16x8*)(vts[cur] + vdh * 64 + ((4 + lg) ^ swv) * 8);
      o[n] = __builtin_amdgcn_mfma_f32_16x16x32_bf16(pa0, v0f, o[n], 0, 0, 0);
      o[n] = __builtin_amdgcn_mfma_f32_16x16x32_bf16(pa1, v1f, o[n], 0, 0, 0);
    }
    __builtin_amdgcn_s_setprio(0);
  };

  for (int kvt = k0t; kvt < k1t; ++kvt) {
    const int nxt = cur ^ 1;
    const bool pf = (kvt + 1 < k1t);
    if (pf) {
      const int kv1 = (kvt + 1) * 64;
#pragma unroll
      for (int r = 0; r < 2; ++r) {
        int c = tid + r * 256, row = c >> 3, p = c & 7;
        GLD16(kb + (size_t)(kv1 + row) * rs + (p ^ (row & 7)) * 8, ks[nxt] + c * 8);
      }
      vr0 = *(const float4*)(vb + (size_t)(kv1 + 2 * vrow2) * rs + vseg * 8);
      vr1 = *(const float4*)(vb + (size_t)(kv1 + 2 * vrow2 + 1) * rs + vseg * 8);
    }
    process(qh0, qh1, kvt == qhi, m_hi, l_hi, o_hi);
    if (kvt <= qlo) process(ql0, ql1, kvt == qlo, m_lo, l_lo, o_lo);
    if (pf) {
      const unsigned short* u0 = (const unsigned short*)&vr0;
      const unsigned short* u1 = (const unsigned short*)&vr1;
#pragma unroll
      for (int i = 0; i < 8; ++i) {
        const int dh = vseg * 8 + i;
        const int phys = (vrow2 >> 2) ^ (dh & 7) ^ ((dh >> 3) & 7);
        unsigned int pk = (unsigned int)u0[i] | ((unsigned int)u1[i] << 16);
        *(unsigned int*)(vts[nxt] + dh * 64 + phys * 8 + 2 * (vrow2 & 3)) = pk;
      }
    }
    __syncthreads();
    cur = nxt;
  }
  // epilogue: normalized partials + per-row m,l
  const float linv_h = (l_hi > 0.f) ? 1.0f / l_hi : 0.f;
  const float linv_l = (l_lo > 0.f) ? 1.0f / l_lo : 0.f;
  __hip_bfloat16* poh = po + (size_t)hf * 4096 * 1024;
#pragma unroll
  for (int j = 0; j < 4; ++j) {
    const float lih = __shfl(linv_h, lg * 4 + j);
    const float lil = __shfl(linv_l, lg * 4 + j);
    size_t rowh = (size_t)b * 2048 + q0hi + w * 16 + lg * 4 + j;
    size_t rowl = (size_t)b * 2048 + q0lo + w * 16 + lg * 4 + j;
#pragma unroll
    for (int n = 0; n < 4; ++n) {
      const int col = h * 64 + n * 16 + lr;
      poh[rowh * 1024 + col] = __float2bfloat16(o_hi[n][j] * lih);
      poh[rowl * 1024 + col] = __float2bfloat16(o_lo[n][j] * lil);
    }
  }
  if (lg == 0 && h == 0) {
  }
  if (lg == 0) {  // one writer per row (lr spans 16 rows per wave); per-h dup is benign-free? no:
    // rows are per-(b,qtp) only; restrict to h==0 would lose m/l for h!=0.
  }
  // NOTE: m/l are PER-ROW PER-HEAD? No — softmax rows are (b,h,q): pm must be
  // indexed by head too. Store pm/pl as [2][16][4096] (h-major slices).
  if (lg == 0) {
    const int rh = b * 2048 + q0hi + w * 16 + lr;
    const int rl = b * 2048 + q0lo + w * 16 + lr;
    float* pmh = pm + ((size_t)hf * 16 + h) * 4096;
    float* plh = pl + ((size_t)hf * 16 + h) * 4096;
    pmh[rh] = m_hi; plh[rh] = l_hi;
    pmh[rl] = m_lo; plh[rl] = l_lo;
  }
}

// ------- merge two KV-halves: o = (o0*w0 + o1*w1)/(w0+w1) -------------------
// po [2][4096][1024] normalized bf16; pm/pl [2][16][4096] per (hf,h,row).
// 2048 blocks x 256 thr; thread -> (row, 8-col group). col -> h = col>>6.
template <int DO_RESID>
__global__ __launch_bounds__(256) void attn_merge(
    const __hip_bfloat16* __restrict__ po, const float* __restrict__ pm,
    const float* __restrict__ pl, __hip_bfloat16* __restrict__ outb, int ob_off,
    const __hip_bfloat16* __restrict__ xg, __hip_bfloat16* __restrict__ residb) {
  const int t = blockIdx.x * 256 + threadIdx.x;
  const int row = t >> 7, c8 = (t & 127) * 8;
  const int h = c8 >> 6;
  const float m0 = pm[(size_t)h * 4096 + row], l0 = pl[(size_t)h * 4096 + row];
  const float m1 = pm[(size_t)(16 + h) * 4096 + row], l1 = pl[(size_t)(16 + h) * 4096 + row];
  const float m = fmaxf(m0, m1);
  float w0 = l0 * __expf(m0 - m), w1 = l1 * __expf(m1 - m);
  const float inv = 1.0f / (w0 + w1);
  w0 *= inv; w1 *= inv;
  const size_t base = (size_t)row * 1024 + c8;
  uint4 a = *(const uint4*)((const unsigned short*)po + base);
  uint4 bq = *(const uint4*)((const unsigned short*)po + (size_t)4096 * 1024 + base);
  const unsigned short* ua = (const unsigned short*)&a;
  const unsigned short* ub = (const unsigned short*)&bq;
  unsigned short om[8], rm[8];
#pragma unroll
  for (int i = 0; i < 8; ++i) {
    float v = bf2f(ua[i]) * w0 + bf2f(ub[i]) * w1;
    om[i] = f2bf(v);
    if constexpr (DO_RESID) {
      rm[i] = f2bf(bf2f(((const unsigned short*)xg)[base + i]) - v);
    }
  }
  *(uint4*)((unsigned short*)outb + (size_t)row * 2048 + ob_off + c8) = *(uint4*)om;
  if constexpr (DO_RESID)
    *(uint4*)((unsigned short*)residb + base) = *(uint4*)rm;
}

extern "C" void kernel_launch(void* const* d_in, const int* in_sizes, int n_in,
                              void* d_out, int out_size, void* d_ws, size_t ws_size,
                              hipStream_t stream) {
  const float* x     = (const float*)d_in[0];
  const float* Wqkv0 = (const float*)d_in[1];
  const float* bqkv0 = (const float*)d_in[2];
  const float* Wqkv1 = (const float*)d_in[3];
  const float* bqkv1 = (const float*)d_in[4];
  const float* Wg    = (const float*)d_in[5];
  const float* bg    = (const float*)d_in[6];
  const float* Wo    = (const float*)d_in[7];
  const float* bo    = (const float*)d_in[8];
  float* out = (float*)d_out;

  char* ws = (char*)d_ws;
  __hip_bfloat16* xb   = (__hip_bfloat16*)(ws);              // 8 MB
  __hip_bfloat16* qkv  = (__hip_bfloat16*)(ws + 8388608);    // 24 MB
  __hip_bfloat16* po   = (__hip_bfloat16*)(ws + 33554432);   // 16 MB partials
  float*          pm   = (float*)(ws + 50331648);            // 512 KB [2][16][4096]
  float*          pl   = (float*)(ws + 50855936);            // 512 KB
  __hip_bfloat16* catb = (__hip_bfloat16*)(ws + 67108864);   // 16 MB [pred|corr]
  __hip_bfloat16* Wt0  = (__hip_bfloat16*)(ws + 83886080);   // 6 MB
  __hip_bfloat16* Wt1  = (__hip_bfloat16*)(ws + 90177536);   // 6 MB
  __hip_bfloat16* Wgt  = (__hip_bfloat16*)(ws + 96468992);   // 4 MB
  __hip_bfloat16* Wot  = (__hip_bfloat16*)(ws + 100663296);  // 2 MB

  prep_batch<<<13312, 256, 0, stream>>>(Wqkv0, Wt0, Wqkv1, Wt1, Wg, Wgt,
                                        Wo, Wot, x, xb);
  // qkv0 = x @ Wqkv0 + b
  gemm_bf16<0><<<768, 256, 0, stream>>>(xb, Wt0, bqkv0, (void*)qkv,
                                        nullptr, nullptr, 4096, 3072, 1024);
  // attn0 split-K -> partials; merge -> catb[:, :1024] + residb (xb)
  attn_kernel<<<dim3(16, 16, 4), 256, 0, stream>>>(qkv, po, pm, pl);
  attn_merge<1><<<2048, 256, 0, stream>>>(po, pm, pl, catb, 0, xb, xb);
  // qkv1 = (x - pred) @ Wqkv1 + b
  gemm_bf16<0><<<768, 256, 0, stream>>>(xb, Wt1, bqkv1, (void*)qkv,
                                        nullptr, nullptr, 4096, 3072, 1024);
  // attn1 -> merge -> catb[:, 1024:]
  attn_kernel<<<dim3(16, 16, 4), 256, 0, stream>>>(qkv, po, pm, pl);
  attn_merge<0><<<2048, 256, 0, stream>>>(po, pm, pl, catb, 1024, nullptr, nullptr);
  // preout = sigmoid(cat @ Wg + bg) * corr + pred   (into xb)
  gemm_bf16<1><<<256, 256, 0, stream>>>(catb, Wgt, bg, (void*)xb,
                                        catb + 1024, catb, 4096, 1024, 2048);
  // out = preout @ Wo + bo (fp32)
  gemm_bf16<2><<<256, 256, 0, stream>>>(xb, Wot, bo, (void*)out,
                                        nullptr, nullptr, 4096, 1024, 1024);
}

// Round 27
// 282.746 us; speedup vs baseline: 1.0388x; 1.0388x over previous
//
#include <hip/hip_runtime.h>
#include <hip/hip_bf16.h>

// BoostedCausalAttention: bf16 MFMA pipeline
// B=2 T=2048 D=1024 H=16 DH=64, fp32 in/out, bf16 internal compute.
// R6 589 -> R8 475 -> R9 352.9 -> R15 309.3 -> R17 302.2 -> R19 297.4 ->
// R21 287.0 -> R24 (verified) 283.1 -> R25 (reverted) split-K 293.7.
// R26 (== R24) FAILED POST-TIMING revalidation (0.0396 vs 0.0078 first-call):
//   flaky replay race. Only in-place global aliasing in the pipeline:
//   attn0 reads AND writes xb (fused resid, since R22).
// R27: resid writes to a SEPARATE residb buffer (ws+32MB, free); qkv1 reads
//   residb. No buffer is both read and written by one kernel anywhere now.
//   Everything else identical to R24.

typedef __bf16 bf16x8 __attribute__((ext_vector_type(8)));
typedef float f32x4 __attribute__((ext_vector_type(4)));

__device__ __forceinline__ unsigned short f2bf(float f) {
  union { __hip_bfloat16 h; unsigned short u; } cv;
  cv.h = __float2bfloat16(f);
  return cv.u;
}

#define GLD16(gp, lp) __builtin_amdgcn_global_load_lds(                      \
    (const __attribute__((address_space(1))) void*)(gp),                     \
    (__attribute__((address_space(3))) void*)(lp), 16, 0, 0)

// ---- batched prep: 4x transpose_cast + x cast in one dispatch --------------
__global__ __launch_bounds__(256) void prep_batch(
    const float* __restrict__ W0, __hip_bfloat16* __restrict__ Wt0,
    const float* __restrict__ W1, __hip_bfloat16* __restrict__ Wt1,
    const float* __restrict__ Wg, __hip_bfloat16* __restrict__ Wgt,
    const float* __restrict__ Wo, __hip_bfloat16* __restrict__ Wot,
    const float* __restrict__ x, __hip_bfloat16* __restrict__ xb) {
  const int bid = blockIdx.x;
  if (bid >= 9216) {  // x cast
    size_t e = (((size_t)(bid - 9216)) * 256 + threadIdx.x) * 4;
    float4 v = *(const float4*)(x + e);
    ushort4 o;
    o.x = f2bf(v.x); o.y = f2bf(v.y); o.z = f2bf(v.z); o.w = f2bf(v.w);
    *(ushort4*)((unsigned short*)xb + e) = o;
    return;
  }
  const float* in; __hip_bfloat16* out; int R, C, base;
  if (bid < 3072)      { in = W0; out = Wt0; R = 1024; C = 3072; base = 0; }
  else if (bid < 6144) { in = W1; out = Wt1; R = 1024; C = 3072; base = 3072; }
  else if (bid < 8192) { in = Wg; out = Wgt; R = 2048; C = 1024; base = 6144; }
  else                 { in = Wo; out = Wot; R = 1024; C = 1024; base = 8192; }
  const int local = bid - base, nbx = C / 32;
  const int bx = (local % nbx) * 32, by = (local / nbx) * 32;
  const int tx = threadIdx.x & 31, ty = threadIdx.x >> 5;
  __shared__ float t[32][33];
#pragma unroll
  for (int i = 0; i < 32; i += 8)
    t[ty + i][tx] = in[(size_t)(by + ty + i) * C + bx + tx];
  __syncthreads();
#pragma unroll
  for (int i = 0; i < 32; i += 8)
    out[(size_t)(bx + ty + i) * R + by + tx] = __float2bfloat16(t[tx][ty + i]);
}

// ------- bf16 MFMA GEMM, 128x128 tile, BK=32, dbuf, T1 XCD swizzle ----------
// 1-D grid (must be %8==0). swz=(bid&7)*cpx+(bid>>3); bx=swz%nbx (x-fastest).
// EPI 0: bf16 acc+bias; EPI 1: bf16 sigmoid(acc+bias)*aux0+aux1 (aux bf16,
// stride 2048); EPI 2: fp32 acc+bias.
template <int EPI>
__global__ __launch_bounds__(256) void gemm_bf16(
    const __hip_bfloat16* __restrict__ A, const __hip_bfloat16* __restrict__ Bt,
    const float* __restrict__ bias, void* __restrict__ outp,
    const __hip_bfloat16* __restrict__ aux0, const __hip_bfloat16* __restrict__ aux1,
    int M, int N, int K) {
  __shared__ __hip_bfloat16 As[2][128 * 32];
  __shared__ __hip_bfloat16 Bs[2][128 * 32];
  const int tid = threadIdx.x;
  const int lane = tid & 63, wid = tid >> 6;
  const int wr = wid >> 1, wc = wid & 1;
  const int lr = lane & 15, lk = (lane >> 4) * 8;
  const int nbx = N >> 7;
  const int cpx = gridDim.x >> 3;
  const int swz = (blockIdx.x & 7) * cpx + (blockIdx.x >> 3);
  const size_t bcol = (size_t)(swz % nbx) * 128;
  const size_t brow = (size_t)(swz / nbx) * 128;
  f32x4 acc[4][4] = {};
#pragma unroll
  for (int r = 0; r < 2; ++r) {
    int c = tid + r * 256;
    GLD16(A + (brow + (size_t)(c >> 2)) * K + (c & 3) * 8, As[0] + c * 8);
    GLD16(Bt + (bcol + (size_t)(c >> 2)) * K + (c & 3) * 8, Bs[0] + c * 8);
  }
  __syncthreads();
  int cur = 0;
  for (int k0 = 0; k0 < K; k0 += 32) {
    const int nxt = cur ^ 1;
    if (k0 + 32 < K) {
#pragma unroll
      for (int r = 0; r < 2; ++r) {
        int c = tid + r * 256;
        GLD16(A + (brow + (size_t)(c >> 2)) * K + k0 + 32 + (c & 3) * 8,
              As[nxt] + c * 8);
        GLD16(Bt + (bcol + (size_t)(c >> 2)) * K + k0 + 32 + (c & 3) * 8,
              Bs[nxt] + c * 8);
      }
    }
    bf16x8 a[4], b[4];
#pragma unroll
    for (int m = 0; m < 4; ++m)
      a[m] = *(const bf16x8*)(As[cur] + (wr * 64 + m * 16 + lr) * 32 + lk);
#pragma unroll
    for (int n = 0; n < 4; ++n)
      b[n] = *(const bf16x8*)(Bs[cur] + (wc * 64 + n * 16 + lr) * 32 + lk);
#pragma unroll
    for (int m = 0; m < 4; ++m)
#pragma unroll
      for (int n = 0; n < 4; ++n)
        acc[m][n] = __builtin_amdgcn_mfma_f32_16x16x32_bf16(a[m], b[n], acc[m][n], 0, 0, 0);
    __syncthreads();
    cur = nxt;
  }
  const int r0 = (lane >> 4) * 4, cn = lane & 15;
#pragma unroll
  for (int m = 0; m < 4; ++m)
#pragma unroll
    for (int n = 0; n < 4; ++n) {
      size_t col = bcol + wc * 64 + n * 16 + cn;
      float bv = bias[col];
#pragma unroll
      for (int j = 0; j < 4; ++j) {
        size_t row = brow + wr * 64 + m * 16 + r0 + j;
        float v = acc[m][n][j] + bv;
        if constexpr (EPI == 1) {
          float g = 1.0f / (1.0f + __expf(-v));
          float a0 = __bfloat162float(aux0[row * 2048 + col]);
          float a1 = __bfloat162float(aux1[row * 2048 + col]);
          ((__hip_bfloat16*)outp)[row * N + col] = __float2bfloat16(g * a0 + a1);
        } else if constexpr (EPI == 2) {
          ((float*)outp)[row * N + col] = v;
        } else {
          ((__hip_bfloat16*)outp)[row * N + col] = __float2bfloat16(v);
        }
      }
    }
}

// ------- causal flash attention V5e (R24 body; resid to SEPARATE buffer) ----
__global__ __launch_bounds__(256) void attn_kernel(
    const __hip_bfloat16* __restrict__ qkv,
    __hip_bfloat16* __restrict__ outb, int ob_off,
    const __hip_bfloat16* __restrict__ xg, __hip_bfloat16* __restrict__ residb) {
  const int b = blockIdx.z, h = blockIdx.y, qtp = blockIdx.x;
  const int qlo = qtp, qhi = 31 - qtp;
  const int q0lo = qlo * 64, q0hi = qhi * 64;
  __shared__ __hip_bfloat16 ks[2][64 * 64];
  __shared__ __hip_bfloat16 vts[2][64 * 64];  // V^T [dh][kv], swizzled
  __shared__ __hip_bfloat16 qps[8192];        // Q_hi|Q_lo staging -> ps_hi|ps_lo
  const int tid = threadIdx.x, lane = tid & 63, w = tid >> 6;
  const int lr = lane & 15, lg = lane >> 4;
  const int sw = lr & 7;
  const size_t rs = 3072;
  const __hip_bfloat16* qbh = qkv + ((size_t)b * 2048 + q0hi) * rs + h * 64;
  const __hip_bfloat16* qbl = qkv + ((size_t)b * 2048 + q0lo) * rs + h * 64;
  const __hip_bfloat16* kb = qkv + (size_t)b * 2048 * rs + 1024 + h * 64;
  const __hip_bfloat16* vb = qkv + (size_t)b * 2048 * rs + 2048 + h * 64;

  const int vrow2 = tid >> 3, vseg = tid & 7;
  float4 vr0, vr1;
#pragma unroll
  for (int r = 0; r < 2; ++r) {
    int c = tid + r * 256, row = c >> 3, p = c & 7;
    GLD16(qbh + (size_t)row * rs + (p ^ (row & 7)) * 8, qps + c * 8);
    GLD16(qbl + (size_t)row * rs + (p ^ (row & 7)) * 8, qps + 4096 + c * 8);
    GLD16(kb + (size_t)row * rs + (p ^ (row & 7)) * 8, ks[0] + c * 8);
  }
  vr0 = *(const float4*)(vb + (size_t)(2 * vrow2) * rs + vseg * 8);
  vr1 = *(const float4*)(vb + (size_t)(2 * vrow2 + 1) * rs + vseg * 8);
  __syncthreads();
  const int qrow = w * 16 + lr;
  const bf16x8 qh0 = *(const bf16x8*)(qps + qrow * 64 + ((lg) ^ (qrow & 7)) * 8);
  const bf16x8 qh1 = *(const bf16x8*)(qps + qrow * 64 + ((4 + lg) ^ (qrow & 7)) * 8);
  const bf16x8 ql0 = *(const bf16x8*)(qps + 4096 + qrow * 64 + ((lg) ^ (qrow & 7)) * 8);
  const bf16x8 ql1 = *(const bf16x8*)(qps + 4096 + qrow * 64 + ((4 + lg) ^ (qrow & 7)) * 8);
  {
    const unsigned short* u0 = (const unsigned short*)&vr0;
    const unsigned short* u1 = (const unsigned short*)&vr1;
#pragma unroll
    for (int i = 0; i < 8; ++i) {
      const int dh = vseg * 8 + i;
      const int phys = (vrow2 >> 2) ^ (dh & 7) ^ ((dh >> 3) & 7);
      unsigned int pk = (unsigned int)u0[i] | ((unsigned int)u1[i] << 16);
      *(unsigned int*)(vts[0] + dh * 64 + phys * 8 + 2 * (vrow2 & 3)) = pk;
    }
  }
  __syncthreads();  // Q frags in regs; qps now free for ps

  __hip_bfloat16* psh = qps + w * 1024;
  __hip_bfloat16* psl = qps + 4096 + w * 1024;
  float m_hi = -1e30f, l_hi = 0.f, m_lo = -1e30f, l_lo = 0.f;
  f32x4 o_hi[4] = {}, o_lo[4] = {};
  int cur = 0;

  auto process = [&](const bf16x8& qa0, const bf16x8& qa1, bool diag,
                     float& m_run, float& l_run, f32x4* o, __hip_bfloat16* psw) {
    f32x4 s4[4] = {};
    __builtin_amdgcn_s_setprio(1);
#pragma unroll
    for (int n = 0; n < 4; ++n) {
      const int kr = n * 16 + lr;
      bf16x8 k0f = *(const bf16x8*)(ks[cur] + kr * 64 + ((lg) ^ sw) * 8);
      bf16x8 k1f = *(const bf16x8*)(ks[cur] + kr * 64 + ((4 + lg) ^ sw) * 8);
      s4[n] = __builtin_amdgcn_mfma_f32_16x16x32_bf16(k0f, qa0, s4[n], 0, 0, 0);
      s4[n] = __builtin_amdgcn_mfma_f32_16x16x32_bf16(k1f, qa1, s4[n], 0, 0, 0);
    }
    __builtin_amdgcn_s_setprio(0);
    float p[4][4];
    float mloc = -1e30f;
#pragma unroll
    for (int n = 0; n < 4; ++n)
#pragma unroll
      for (int j = 0; j < 4; ++j) {
        float v = s4[n][j] * 0.125f;
        if (diag && (n * 16 + lg * 4 + j) > (w * 16 + lr)) v = -1e30f;
        p[n][j] = v;
        mloc = fmaxf(mloc, v);
      }
    mloc = fmaxf(mloc, __shfl_xor(mloc, 16));
    mloc = fmaxf(mloc, __shfl_xor(mloc, 32));
    if (!__all(mloc - m_run <= 8.0f)) {  // T13 defer-max
      const float mn = fmaxf(m_run, mloc);
      const float sc = __expf(m_run - mn);
      m_run = mn;
      l_run *= sc;
      float scb[4];
#pragma unroll
      for (int j = 0; j < 4; ++j) scb[j] = __shfl(sc, lg * 4 + j);
#pragma unroll
      for (int n = 0; n < 4; ++n)
#pragma unroll
        for (int j = 0; j < 4; ++j) o[n][j] *= scb[j];
    }
    float ls = 0.f;
#pragma unroll
    for (int n = 0; n < 4; ++n)
#pragma unroll
      for (int j = 0; j < 4; ++j) { p[n][j] = __expf(p[n][j] - m_run); ls += p[n][j]; }
    ls += __shfl_xor(ls, 16);
    ls += __shfl_xor(ls, 32);
    l_run += ls;
#pragma unroll
    for (int n = 0; n < 4; ++n)
#pragma unroll
      for (int j = 0; j < 4; ++j)
        psw[lr * 64 + ((n * 2 + (lg >> 1)) ^ sw) * 8 + (lg & 1) * 4 + j] =
            __float2bfloat16(p[n][j]);
    bf16x8 pa0 = *(const bf16x8*)(&psw[lr * 64 + ((lg) ^ sw) * 8]);
    bf16x8 pa1 = *(const bf16x8*)(&psw[lr * 64 + ((4 + lg) ^ sw) * 8]);
    __builtin_amdgcn_s_setprio(1);
#pragma unroll
    for (int n = 0; n < 4; ++n) {
      const int vdh = n * 16 + lr;
      const int swv = (vdh & 7) ^ ((vdh >> 3) & 7);
      bf16x8 v0f = *(const bf16x8*)(vts[cur] + vdh * 64 + ((lg) ^ swv) * 8);
      bf16x8 v1f = *(const bf16x8*)(vts[cur] + vdh * 64 + ((4 + lg) ^ swv) * 8);
      o[n] = __builtin_amdgcn_mfma_f32_16x16x32_bf16(pa0, v0f, o[n], 0, 0, 0);
      o[n] = __builtin_amdgcn_mfma_f32_16x16x32_bf16(pa1, v1f, o[n], 0, 0, 0);
    }
    __builtin_amdgcn_s_setprio(0);
  };

  for (int kvt = 0; kvt <= qhi; ++kvt) {
    const int nxt = cur ^ 1;
    const bool pf = (kvt < qhi);
    if (pf) {
      const int kv1 = (kvt + 1) * 64;
#pragma unroll
      for (int r = 0; r < 2; ++r) {
        int c = tid + r * 256, row = c >> 3, p = c & 7;
        GLD16(kb + (size_t)(kv1 + row) * rs + (p ^ (row & 7)) * 8, ks[nxt] + c * 8);
      }
      vr0 = *(const float4*)(vb + (size_t)(kv1 + 2 * vrow2) * rs + vseg * 8);
      vr1 = *(const float4*)(vb + (size_t)(kv1 + 2 * vrow2 + 1) * rs + vseg * 8);
    }
    process(qh0, qh1, kvt == qhi, m_hi, l_hi, o_hi, psh);
    if (kvt <= qlo) process(ql0, ql1, kvt == qlo, m_lo, l_lo, o_lo, psl);
    if (pf) {
      const unsigned short* u0 = (const unsigned short*)&vr0;
      const unsigned short* u1 = (const unsigned short*)&vr1;
#pragma unroll
      for (int i = 0; i < 8; ++i) {
        const int dh = vseg * 8 + i;
        const int phys = (vrow2 >> 2) ^ (dh & 7) ^ ((dh >> 3) & 7);
        unsigned int pk = (unsigned int)u0[i] | ((unsigned int)u1[i] << 16);
        *(unsigned int*)(vts[nxt] + dh * 64 + phys * 8 + 2 * (vrow2 & 3)) = pk;
      }
    }
    __syncthreads();
    cur = nxt;
  }
  const float linv_h = 1.0f / l_hi, linv_l = 1.0f / l_lo;
#pragma unroll
  for (int j = 0; j < 4; ++j) {
    const float lih = __shfl(linv_h, lg * 4 + j);
    const float lil = __shfl(linv_l, lg * 4 + j);
    size_t rowh = (size_t)b * 2048 + q0hi + w * 16 + lg * 4 + j;
    size_t rowl = (size_t)b * 2048 + q0lo + w * 16 + lg * 4 + j;
#pragma unroll
    for (int n = 0; n < 4; ++n) {
      float vh = o_hi[n][j] * lih, vl = o_lo[n][j] * lil;
      const int col = h * 64 + n * 16 + lr;
      outb[rowh * 2048 + ob_off + col] = __float2bfloat16(vh);
      outb[rowl * 2048 + ob_off + col] = __float2bfloat16(vl);
      if (ob_off == 0) {  // fused resid -> SEPARATE residb buffer (no aliasing)
        float xh = __bfloat162float(xg[rowh * 1024 + col]);
        float xl = __bfloat162float(xg[rowl * 1024 + col]);
        residb[rowh * 1024 + col] = __float2bfloat16(xh - vh);
        residb[rowl * 1024 + col] = __float2bfloat16(xl - vl);
      }
    }
  }
}

extern "C" void kernel_launch(void* const* d_in, const int* in_sizes, int n_in,
                              void* d_out, int out_size, void* d_ws, size_t ws_size,
                              hipStream_t stream) {
  const float* x     = (const float*)d_in[0];
  const float* Wqkv0 = (const float*)d_in[1];
  const float* bqkv0 = (const float*)d_in[2];
  const float* Wqkv1 = (const float*)d_in[3];
  const float* bqkv1 = (const float*)d_in[4];
  const float* Wg    = (const float*)d_in[5];
  const float* bg    = (const float*)d_in[6];
  const float* Wo    = (const float*)d_in[7];
  const float* bo    = (const float*)d_in[8];
  float* out = (float*)d_out;

  char* ws = (char*)d_ws;
  __hip_bfloat16* xb     = (__hip_bfloat16*)(ws);              // 8 MB (bf16(x), then preout)
  __hip_bfloat16* qkv    = (__hip_bfloat16*)(ws + 8388608);    // 24 MB (qkv0 then qkv1)
  __hip_bfloat16* residb = (__hip_bfloat16*)(ws + 33554432);   // 8 MB (x - pred)
  __hip_bfloat16* catb   = (__hip_bfloat16*)(ws + 67108864);   // 16 MB [pred | corr] bf16
  __hip_bfloat16* Wt0    = (__hip_bfloat16*)(ws + 83886080);   // 6 MB
  __hip_bfloat16* Wt1    = (__hip_bfloat16*)(ws + 90177536);   // 6 MB
  __hip_bfloat16* Wgt    = (__hip_bfloat16*)(ws + 96468992);   // 4 MB
  __hip_bfloat16* Wot    = (__hip_bfloat16*)(ws + 100663296);  // 2 MB

  // all prep in one dispatch
  prep_batch<<<13312, 256, 0, stream>>>(Wqkv0, Wt0, Wqkv1, Wt1, Wg, Wgt,
                                        Wo, Wot, x, xb);

  // qkv0 = x @ Wqkv0 + b  (128^2 dbuf + T1, 768 blocks)
  gemm_bf16<0><<<768, 256, 0, stream>>>(xb, Wt0, bqkv0, (void*)qkv,
                                        nullptr, nullptr, 4096, 3072, 1024);
  // attn0: pred -> catb[:, :1024]; fused residb = bf16(xb - pred) -> residb
  attn_kernel<<<dim3(16, 16, 2), 256, 0, stream>>>(qkv, catb, 0, xb, residb);
  // qkv1 = (x - pred) @ Wqkv1 + b   (reads residb)
  gemm_bf16<0><<<768, 256, 0, stream>>>(residb, Wt1, bqkv1, (void*)qkv,
                                        nullptr, nullptr, 4096, 3072, 1024);
  // attn1: corr -> catb[:, 1024:]
  attn_kernel<<<dim3(16, 16, 2), 256, 0, stream>>>(qkv, catb, 1024, nullptr, nullptr);
  // preout = sigmoid(cat @ Wg + bg) * corr + pred   (into xb, aux from catb)
  gemm_bf16<1><<<256, 256, 0, stream>>>(catb, Wgt, bg, (void*)xb,
                                        catb + 1024, catb, 4096, 1024, 2048);
  // out = preout @ Wo + bo (fp32)
  gemm_bf16<2><<<256, 256, 0, stream>>>(xb, Wot, bo, (void*)out,
                                        nullptr, nullptr, 4096, 1024, 1024);
}